// Round 12
// baseline (191.774 us; speedup 1.0000x reference)
//
#include <hip/hip_runtime.h>
#include <math.h>

#define BSZ 2
#define TSEQ 2048
#define CEMB 1024
#define NHEAD 16
#define HDIM 64

typedef float f32x4 __attribute__((ext_vector_type(4)));
typedef short bf16x8 __attribute__((ext_vector_type(8)));

typedef __attribute__((address_space(3))) char lds_char;
typedef __attribute__((address_space(1))) const char gbl_char;

__device__ __forceinline__ void g2l16(const void* g, void* l) {
    // async global->LDS, 16B per lane; LDS dest = wave-uniform base + lane*16
    __builtin_amdgcn_global_load_lds((const gbl_char*)g, (lds_char*)l, 16, 0, 0);
}

__device__ __forceinline__ unsigned short f2bf(float x) {
    unsigned u = __float_as_uint(x);
    unsigned r = ((u >> 16) & 1u) + 0x7fffu;   // round-to-nearest-even
    return (unsigned short)((u + r) >> 16);
}

__device__ __forceinline__ unsigned pkbf(float lo, float hi) {
    // 2x f32 -> packed 2x bf16 in one VALU op (guide T12 recipe; no builtin)
    unsigned r;
    asm("v_cvt_pk_bf16_f32 %0, %1, %2" : "=v"(r) : "v"(lo), "v"(hi));
    return r;
}

// ---------------------------------------------------------------------------
// fp32 -> bf16 elementwise (8 elems/thread, 16B stores)
// ---------------------------------------------------------------------------
__global__ __launch_bounds__(256) void conv_f32_bf16(
    const float* __restrict__ in, unsigned short* __restrict__ out)
{
    size_t i = ((size_t)blockIdx.x * 256 + threadIdx.x) * 8;
    float4 a = *(const float4*)(in + i);
    float4 b = *(const float4*)(in + i + 4);
    union { unsigned short u[8]; uint4 v; } pk;
    pk.u[0] = f2bf(a.x); pk.u[1] = f2bf(a.y); pk.u[2] = f2bf(a.z); pk.u[3] = f2bf(a.w);
    pk.u[4] = f2bf(b.x); pk.u[5] = f2bf(b.y); pk.u[6] = f2bf(b.z); pk.u[7] = f2bf(b.w);
    *(uint4*)(out + i) = pk.v;
}

// ---------------------------------------------------------------------------
// fp32 [K][N] -> bf16 transposed [N][K]
// ---------------------------------------------------------------------------
__global__ __launch_bounds__(256) void conv_transpose_bf16(
    const float* __restrict__ w, unsigned short* __restrict__ wT, int K, int N)
{
    __shared__ float t[32][33];
    const int n0 = blockIdx.x * 32, k0 = blockIdx.y * 32;
    const int tx = threadIdx.x & 31, ty = threadIdx.x >> 5;  // 32 x 8
    #pragma unroll
    for (int i = 0; i < 4; ++i)
        t[ty + i * 8][tx] = w[(size_t)(k0 + ty + i * 8) * N + n0 + tx];
    __syncthreads();
    #pragma unroll
    for (int i = 0; i < 4; ++i) {
        int r = ty + i * 8;
        wT[(size_t)(n0 + r) * K + k0 + tx] = f2bf(t[tx][r]);
    }
}

// ---------------------------------------------------------------------------
// bf16 MFMA GEMM: C[M,N] = A[M,K] @ BT[N,K]^T + bias  (unchanged)
// ---------------------------------------------------------------------------
template <int EPI>
__global__ __launch_bounds__(256) void gemm_mfma(
    const unsigned short* __restrict__ A, const unsigned short* __restrict__ BT,
    const float* __restrict__ bias,
    unsigned short* __restrict__ qo, unsigned short* __restrict__ ko,
    unsigned short* __restrict__ vo, float* __restrict__ fo,
    int M, int N, int K)
{
    __shared__ __align__(16) char sA[128 * 64 * 2];
    __shared__ __align__(16) char sB[128 * 64 * 2];

    const int tid = threadIdx.x;
    const int lane = tid & 63;
    const int wid = tid >> 6;
    const int wm = wid >> 1, wn = wid & 1;
    const int row0 = blockIdx.y * 128;
    const int col0 = blockIdx.x * 128;

    f32x4 acc[4][4] = {};

    for (int k0 = 0; k0 < K; k0 += 64) {
        __syncthreads();
        #pragma unroll
        for (int i = 0; i < 4; ++i) {
            int cid = i * 256 + tid;
            int row = cid >> 3, c2 = cid & 7;
            g2l16(&A[(size_t)(row0 + row) * K + k0 + ((c2 ^ (row & 7)) << 3)],
                  sA + ((i * 256 + (tid & 192)) << 4));
        }
        #pragma unroll
        for (int i = 0; i < 4; ++i) {
            int cid = i * 256 + tid;
            int row = cid >> 3, c2 = cid & 7;
            g2l16(&BT[(size_t)(col0 + row) * K + k0 + ((c2 ^ (row & 7)) << 3)],
                  sB + ((i * 256 + (tid & 192)) << 4));
        }
        __syncthreads();

        #pragma unroll
        for (int ks = 0; ks < 2; ++ks) {
            bf16x8 af[4], bf[4];
            #pragma unroll
            for (int mi = 0; mi < 4; ++mi) {
                int row = wm * 64 + mi * 16 + (lane & 15);
                int ch = ((lane >> 4) + 4 * ks) ^ (row & 7);
                af[mi] = *(const bf16x8*)(sA + row * 128 + (ch << 4));
            }
            #pragma unroll
            for (int ni = 0; ni < 4; ++ni) {
                int row = wn * 64 + ni * 16 + (lane & 15);
                int ch = ((lane >> 4) + 4 * ks) ^ (row & 7);
                bf[ni] = *(const bf16x8*)(sB + row * 128 + (ch << 4));
            }
            #pragma unroll
            for (int mi = 0; mi < 4; ++mi)
                #pragma unroll
                for (int ni = 0; ni < 4; ++ni)
                    acc[mi][ni] = __builtin_amdgcn_mfma_f32_16x16x32_bf16(
                        af[mi], bf[ni], acc[mi][ni], 0, 0, 0);
        }
    }

    #pragma unroll
    for (int mi = 0; mi < 4; ++mi) {
        const int rg = row0 + wm * 64 + mi * 16 + (lane >> 4) * 4;
        #pragma unroll
        for (int ni = 0; ni < 4; ++ni) {
            const int cg = col0 + wn * 64 + ni * 16 + (lane & 15);
            const float bv = bias[cg];
            if (EPI == 1) {
                #pragma unroll
                for (int r = 0; r < 4; ++r)
                    fo[(size_t)(rg + r) * N + cg] = acc[mi][ni][r] + bv;
            } else {
                const int region = col0 >> 10;
                if (region < 2) {
                    unsigned short* dst = region ? ko : qo;
                    // fold softmax scale (in exp2 domain) into Q at the source
                    const float sc = region ? 1.f : 0.0450744431f;  // log2(e)/32
                    const int nn = cg - (region << 10);
                    #pragma unroll
                    for (int r = 0; r < 4; ++r)
                        dst[(size_t)(rg + r) * CEMB + nn] = f2bf((acc[mi][ni][r] + bv) * sc);
                } else {
                    const int nloc = cg - 2048;
                    const int h = nloc >> 6, d = nloc & 63;
                    const int b = rg >> 11, t = rg & 2047;
                    ushort4 pk;
                    pk.x = f2bf(acc[mi][ni][0] + bv);
                    pk.y = f2bf(acc[mi][ni][1] + bv);
                    pk.z = f2bf(acc[mi][ni][2] + bv);
                    pk.w = f2bf(acc[mi][ni][3] + bv);
                    *(ushort4*)&vo[(((size_t)b * NHEAD + h) * HDIM + d) * TSEQ + t] = pk;
                }
            }
        }
    }
}

// ---------------------------------------------------------------------------
// MFMA flash attention. Swapped QK^T, kt-loop unrolled x2 (buf bases are
// immediates), all LDS addresses hoisted (loop-invariant), staging pointers
// strength-reduced, s_setprio around MFMA clusters.
// Block map (R11, verified): bh=bid&31 (head->XCD), j=bid>>5,
// qt_raw=((j&7)<<2)|(j>>3), qt=reflect(qt_raw) -> per-CU qt sum == 66.
// ---------------------------------------------------------------------------
__global__ __launch_bounds__(256) void flash_mfma(
    const unsigned short* __restrict__ qb, const unsigned short* __restrict__ kb,
    const unsigned short* __restrict__ vt, unsigned short* __restrict__ ob)
{
    const int bid = blockIdx.x;
    const int bh = bid & 31;
    const int j = bid >> 5;
    const int qt_raw = ((j & 7) << 2) | (j >> 3);
    const int qt = (qt_raw & 1) ? (31 - (qt_raw >> 1)) : (qt_raw >> 1);
    const int b = bh >> 4, h = bh & 15;
    const int q0 = qt * 64;

    __shared__ __align__(16) char sK[2][8192];
    __shared__ __align__(16) char sV[2][8192];
    __shared__ __align__(16) char sP[8192];

    const int tid = threadIdx.x;
    const int lane = tid & 63;
    const int wid = tid >> 6;
    const int g = lane >> 4;
    const int lr = lane & 15;
    const int q7 = lr & 7;

    // ---- invariant staging state (per-lane) ----
    const int srow = tid >> 3;                 // 0..31 (i=0); +32 for i=1
    const int sc2 = tid & 7;
    const int sxor = (sc2 ^ (srow & 7)) << 3;  // same for row and row+32
    const int ldst = (tid & 192) << 4;         // wave-uniform LDS sub-base

    const unsigned short* kp0 = kb + (size_t)(b * TSEQ + srow) * CEMB + h * HDIM + sxor;
    const unsigned short* kp1 = kp0 + (size_t)32 * CEMB;
    const unsigned short* vp0 = vt + (((size_t)b * NHEAD + h) * HDIM + srow) * TSEQ + sxor;
    const unsigned short* vp1 = vp0 + (size_t)32 * TSEQ;

#define STAGE(BUF)                                                  \
    do {                                                            \
        g2l16(kp0, sK[BUF] + ldst);                                 \
        g2l16(kp1, sK[BUF] + 4096 + ldst);                          \
        g2l16(vp0, sV[BUF] + ldst);                                 \
        g2l16(vp1, sV[BUF] + 4096 + ldst);                          \
        kp0 += 64 * CEMB; kp1 += 64 * CEMB;                         \
        vp0 += 64; vp1 += 64;                                       \
    } while (0)

    // stage Q (into sP) + tile 0 into buf 0
    {
        const unsigned short* qp0 = qb + (size_t)(b * TSEQ + q0 + srow) * CEMB + h * HDIM + sxor;
        g2l16(qp0, sP + ldst);
        g2l16(qp0 + (size_t)32 * CEMB, sP + 4096 + ldst);
    }
    STAGE(0);
    __syncthreads();   // drain staging

    // ---- invariant LDS addresses ----
    const int rbase = (wid * 16 + lr) * 128;     // this wave's qrow stripe
    const int cA = (g ^ q7) << 4;                // ks=0 chunk byte
    const int cB = cA ^ 0x40;                    // ks=1 chunk byte (^4 on chunk)
    const char* kA0 = sK[0] + lr * 128 + cA;     // + ni*2048 immediate
    const char* kB0 = sK[0] + lr * 128 + cB;
    const char* kA1 = sK[1] + lr * 128 + cA;
    const char* kB1 = sK[1] + lr * 128 + cB;
    const char* vA0 = sV[0] + lr * 128 + cA;
    const char* vB0 = sV[0] + lr * 128 + cB;
    const char* vA1 = sV[1] + lr * 128 + cA;
    const char* vB1 = sV[1] + lr * 128 + cB;
    const char* prA = sP + rbase + cA;
    const char* prB = sP + rbase + cB;
    char* pw[4];
    #pragma unroll
    for (int ni = 0; ni < 4; ++ni)
        pw[ni] = sP + rbase + ((((2 * ni + (g >> 1))) ^ q7) << 4) + ((g & 1) << 3);

    // Q fragments (Q staged in sP with the same layout as P)
    bf16x8 qf0 = *(const bf16x8*)prA;
    bf16x8 qf1 = *(const bf16x8*)prB;
    __syncthreads();   // all waves have Q before sP becomes the P buffer

    f32x4 o[4] = {};
    float mrow = -INFINITY, lrow = 0.f;
    const int qrow_g = q0 + wid * 16 + lr;

#define COMPUTE(KA, KB, VA, VB, KT)                                           \
    do {                                                                      \
        f32x4 s[4] = {};                                                      \
        __builtin_amdgcn_s_setprio(1);                                        \
        _Pragma("unroll")                                                     \
        for (int ni = 0; ni < 4; ++ni) {                                      \
            s[ni] = __builtin_amdgcn_mfma_f32_16x16x32_bf16(                  \
                *(const bf16x8*)(KA + ni * 2048), qf0, s[ni], 0, 0, 0);       \
            s[ni] = __builtin_amdgcn_mfma_f32_16x16x32_bf16(                  \
                *(const bf16x8*)(KB + ni * 2048), qf1, s[ni], 0, 0, 0);       \
        }                                                                     \
        __builtin_amdgcn_s_setprio(0);                                        \
        if ((KT) == qt) {                                                     \
            const int k0m = (KT) * 64;                                        \
            _Pragma("unroll")                                                 \
            for (int ni = 0; ni < 4; ++ni)                                    \
                _Pragma("unroll")                                             \
                for (int r = 0; r < 4; ++r)                                   \
                    if (k0m + ni * 16 + g * 4 + r > qrow_g) s[ni][r] = -INFINITY; \
        }                                                                     \
        float v = s[0][0];                                                    \
        v = fmaxf(v, s[0][1]); v = fmaxf(v, s[0][2]); v = fmaxf(v, s[0][3]);  \
        v = fmaxf(v, s[1][0]); v = fmaxf(v, s[1][1]); v = fmaxf(v, s[1][2]); v = fmaxf(v, s[1][3]); \
        v = fmaxf(v, s[2][0]); v = fmaxf(v, s[2][1]); v = fmaxf(v, s[2][2]); v = fmaxf(v, s[2][3]); \
        v = fmaxf(v, s[3][0]); v = fmaxf(v, s[3][1]); v = fmaxf(v, s[3][2]); v = fmaxf(v, s[3][3]); \
        v = fmaxf(v, __shfl_xor(v, 16));                                      \
        v = fmaxf(v, __shfl_xor(v, 32));                                      \
        if (!__all(v <= mrow + 8.f)) {                                        \
            const float mnew = fmaxf(mrow, v);                                \
            const float sc = exp2f(mrow - mnew);                              \
            lrow *= sc;                                                       \
            _Pragma("unroll")                                                 \
            for (int ni = 0; ni < 4; ++ni)                                    \
                _Pragma("unroll")                                             \
                for (int r = 0; r < 4; ++r)                                   \
                    o[ni][r] *= sc;                                           \
            mrow = mnew;                                                      \
        }                                                                     \
        float ps = 0.f;                                                       \
        _Pragma("unroll")                                                     \
        for (int ni = 0; ni < 4; ++ni) {                                      \
            const float p0 = exp2f(s[ni][0] - mrow);                          \
            const float p1 = exp2f(s[ni][1] - mrow);                          \
            const float p2 = exp2f(s[ni][2] - mrow);                          \
            const float p3 = exp2f(s[ni][3] - mrow);                          \
            ps += (p0 + p1) + (p2 + p3);                                      \
            uint2 w;                                                          \
            w.x = pkbf(p0, p1);                                               \
            w.y = pkbf(p2, p3);                                               \
            *(uint2*)pw[ni] = w;                                              \
        }                                                                     \
        ps += __shfl_xor(ps, 16);                                             \
        ps += __shfl_xor(ps, 32);                                             \
        lrow += ps;                                                           \
        asm volatile("s_waitcnt lgkmcnt(0)" ::: "memory");                    \
        bf16x8 pf0 = *(const bf16x8*)prA;                                     \
        bf16x8 pf1 = *(const bf16x8*)prB;                                     \
        __builtin_amdgcn_s_setprio(1);                                        \
        _Pragma("unroll")                                                     \
        for (int ni = 0; ni < 4; ++ni) {                                      \
            o[ni] = __builtin_amdgcn_mfma_f32_16x16x32_bf16(                  \
                *(const bf16x8*)(VA + ni * 2048), pf0, o[ni], 0, 0, 0);       \
            o[ni] = __builtin_amdgcn_mfma_f32_16x16x32_bf16(                  \
                *(const bf16x8*)(VB + ni * 2048), pf1, o[ni], 0, 0, 0);       \
        }                                                                     \
        __builtin_amdgcn_s_setprio(0);                                        \
    } while (0)

    for (int kt = 0; kt <= qt; kt += 2) {
        // phase A: compute buf0 (tile kt), prefetch tile kt+1 -> buf1
        if (kt + 1 <= qt) STAGE(1);
        COMPUTE(kA0, kB0, vA0, vB0, kt);
        __syncthreads();  // drains prefetch vmcnt + LDS readers
        if (kt + 1 <= qt) {
            // phase B: compute buf1 (tile kt+1), prefetch tile kt+2 -> buf0
            if (kt + 2 <= qt) STAGE(0);
            COMPUTE(kA1, kB1, vA1, vB1, kt + 1);
            __syncthreads();
        }
    }
#undef COMPUTE
#undef STAGE

    // epilogue: normalize, write O^T into sP as [qrow][d] (swizzled), transpose-read
    const float linv = 1.f / lrow;
    #pragma unroll
    for (int ni = 0; ni < 4; ++ni) {
        uint2 w;
        w.x = pkbf(o[ni][0] * linv, o[ni][1] * linv);
        w.y = pkbf(o[ni][2] * linv, o[ni][3] * linv);
        *(uint2*)pw[ni] = w;
    }
    __syncthreads();
    #pragma unroll
    for (int i = 0; i < 2; ++i) {
        const int cid = i * 256 + tid;
        const int row = cid >> 3;      // qrow 0..63
        const int ch = cid & 7;        // d-chunk
        uint4 val = *(const uint4*)(sP + row * 128 + ((ch ^ (row & 7)) << 4));
        *(uint4*)&ob[(size_t)(b * TSEQ + q0 + row) * CEMB + h * HDIM + ch * 8] = val;
    }
}

// ---------------------------------------------------------------------------
extern "C" void kernel_launch(void* const* d_in, const int* in_sizes, int n_in,
                              void* d_out, int out_size, void* d_ws, size_t ws_size,
                              hipStream_t stream)
{
    (void)in_sizes; (void)n_in; (void)out_size; (void)ws_size;

    const float* x      = (const float*)d_in[0];
    const float* w_qkv  = (const float*)d_in[1];
    const float* b_qkv  = (const float*)d_in[2];
    const float* w_proj = (const float*)d_in[3];
    const float* b_proj = (const float*)d_in[4];
    float* out = (float*)d_out;

    const int M = BSZ * TSEQ;  // 4096
    unsigned short* xb     = (unsigned short*)d_ws;           // [4096][1024]
    unsigned short* wqkvT  = xb     + (size_t)M * CEMB;       // [3072][1024]
    unsigned short* wprojT = wqkvT  + (size_t)3 * CEMB * CEMB;// [1024][1024]
    unsigned short* qbuf   = wprojT + (size_t)CEMB * CEMB;    // [4096][1024] (pre-scaled)
    unsigned short* kbuf   = qbuf   + (size_t)M * CEMB;       // [4096][1024]
    unsigned short* vbuf   = kbuf   + (size_t)M * CEMB;       // [2][16][64][2048]
    unsigned short* attb   = vbuf   + (size_t)M * CEMB;       // [4096][1024]

    conv_f32_bf16<<<dim3((M * CEMB) / 2048), 256, 0, stream>>>(x, xb);
    conv_transpose_bf16<<<dim3(3 * CEMB / 32, CEMB / 32), 256, 0, stream>>>(
        w_qkv, wqkvT, CEMB, 3 * CEMB);
    conv_transpose_bf16<<<dim3(CEMB / 32, CEMB / 32), 256, 0, stream>>>(
        w_proj, wprojT, CEMB, CEMB);

    gemm_mfma<0><<<dim3(3 * CEMB / 128, M / 128), 256, 0, stream>>>(
        xb, wqkvT, b_qkv, qbuf, kbuf, vbuf, nullptr, M, 3 * CEMB, CEMB);

    flash_mfma<<<dim3(32 * 32), 256, 0, stream>>>(qbuf, kbuf, vbuf, attb);

    gemm_mfma<1><<<dim3(CEMB / 128, M / 128), 256, 0, stream>>>(
        attb, wprojT, b_proj, nullptr, nullptr, nullptr, out, M, CEMB, CEMB);
}

// Round 13
// 187.225 us; speedup vs baseline: 1.0243x; 1.0243x over previous
//
#include <hip/hip_runtime.h>
#include <math.h>

#define BSZ 2
#define TSEQ 2048
#define CEMB 1024
#define NHEAD 16
#define HDIM 64

typedef float f32x4 __attribute__((ext_vector_type(4)));
typedef short bf16x8 __attribute__((ext_vector_type(8)));

typedef __attribute__((address_space(3))) char lds_char;
typedef __attribute__((address_space(1))) const char gbl_char;

__device__ __forceinline__ void g2l16(const void* g, void* l) {
    // async global->LDS, 16B per lane; LDS dest = wave-uniform base + lane*16
    __builtin_amdgcn_global_load_lds((const gbl_char*)g, (lds_char*)l, 16, 0, 0);
}

__device__ __forceinline__ unsigned short f2bf(float x) {
    unsigned u = __float_as_uint(x);
    unsigned r = ((u >> 16) & 1u) + 0x7fffu;   // round-to-nearest-even
    return (unsigned short)((u + r) >> 16);
}

__device__ __forceinline__ unsigned pkbf(float lo, float hi) {
    // 2x f32 -> packed 2x bf16 in one VALU op (guide T12 recipe; no builtin)
    unsigned r;
    asm("v_cvt_pk_bf16_f32 %0, %1, %2" : "=v"(r) : "v"(lo), "v"(hi));
    return r;
}

// ---------------------------------------------------------------------------
// fp32 -> bf16 elementwise (8 elems/thread, 16B stores)
// ---------------------------------------------------------------------------
__global__ __launch_bounds__(256) void conv_f32_bf16(
    const float* __restrict__ in, unsigned short* __restrict__ out)
{
    size_t i = ((size_t)blockIdx.x * 256 + threadIdx.x) * 8;
    float4 a = *(const float4*)(in + i);
    float4 b = *(const float4*)(in + i + 4);
    union { unsigned short u[8]; uint4 v; } pk;
    pk.u[0] = f2bf(a.x); pk.u[1] = f2bf(a.y); pk.u[2] = f2bf(a.z); pk.u[3] = f2bf(a.w);
    pk.u[4] = f2bf(b.x); pk.u[5] = f2bf(b.y); pk.u[6] = f2bf(b.z); pk.u[7] = f2bf(b.w);
    *(uint4*)(out + i) = pk.v;
}

// ---------------------------------------------------------------------------
// fp32 [K][N] -> bf16 transposed [N][K]
// ---------------------------------------------------------------------------
__global__ __launch_bounds__(256) void conv_transpose_bf16(
    const float* __restrict__ w, unsigned short* __restrict__ wT, int K, int N)
{
    __shared__ float t[32][33];
    const int n0 = blockIdx.x * 32, k0 = blockIdx.y * 32;
    const int tx = threadIdx.x & 31, ty = threadIdx.x >> 5;  // 32 x 8
    #pragma unroll
    for (int i = 0; i < 4; ++i)
        t[ty + i * 8][tx] = w[(size_t)(k0 + ty + i * 8) * N + n0 + tx];
    __syncthreads();
    #pragma unroll
    for (int i = 0; i < 4; ++i) {
        int r = ty + i * 8;
        wT[(size_t)(n0 + r) * K + k0 + tx] = f2bf(t[tx][r]);
    }
}

// ---------------------------------------------------------------------------
// bf16 MFMA GEMM: C[M,N] = A[M,K] @ BT[N,K]^T + bias  (unchanged)
// ---------------------------------------------------------------------------
template <int EPI>
__global__ __launch_bounds__(256) void gemm_mfma(
    const unsigned short* __restrict__ A, const unsigned short* __restrict__ BT,
    const float* __restrict__ bias,
    unsigned short* __restrict__ qo, unsigned short* __restrict__ ko,
    unsigned short* __restrict__ vo, float* __restrict__ fo,
    int M, int N, int K)
{
    __shared__ __align__(16) char sA[128 * 64 * 2];
    __shared__ __align__(16) char sB[128 * 64 * 2];

    const int tid = threadIdx.x;
    const int lane = tid & 63;
    const int wid = tid >> 6;
    const int wm = wid >> 1, wn = wid & 1;
    const int row0 = blockIdx.y * 128;
    const int col0 = blockIdx.x * 128;

    f32x4 acc[4][4] = {};

    for (int k0 = 0; k0 < K; k0 += 64) {
        __syncthreads();
        #pragma unroll
        for (int i = 0; i < 4; ++i) {
            int cid = i * 256 + tid;
            int row = cid >> 3, c2 = cid & 7;
            g2l16(&A[(size_t)(row0 + row) * K + k0 + ((c2 ^ (row & 7)) << 3)],
                  sA + ((i * 256 + (tid & 192)) << 4));
        }
        #pragma unroll
        for (int i = 0; i < 4; ++i) {
            int cid = i * 256 + tid;
            int row = cid >> 3, c2 = cid & 7;
            g2l16(&BT[(size_t)(col0 + row) * K + k0 + ((c2 ^ (row & 7)) << 3)],
                  sB + ((i * 256 + (tid & 192)) << 4));
        }
        __syncthreads();

        #pragma unroll
        for (int ks = 0; ks < 2; ++ks) {
            bf16x8 af[4], bf[4];
            #pragma unroll
            for (int mi = 0; mi < 4; ++mi) {
                int row = wm * 64 + mi * 16 + (lane & 15);
                int ch = ((lane >> 4) + 4 * ks) ^ (row & 7);
                af[mi] = *(const bf16x8*)(sA + row * 128 + (ch << 4));
            }
            #pragma unroll
            for (int ni = 0; ni < 4; ++ni) {
                int row = wn * 64 + ni * 16 + (lane & 15);
                int ch = ((lane >> 4) + 4 * ks) ^ (row & 7);
                bf[ni] = *(const bf16x8*)(sB + row * 128 + (ch << 4));
            }
            #pragma unroll
            for (int mi = 0; mi < 4; ++mi)
                #pragma unroll
                for (int ni = 0; ni < 4; ++ni)
                    acc[mi][ni] = __builtin_amdgcn_mfma_f32_16x16x32_bf16(
                        af[mi], bf[ni], acc[mi][ni], 0, 0, 0);
        }
    }

    #pragma unroll
    for (int mi = 0; mi < 4; ++mi) {
        const int rg = row0 + wm * 64 + mi * 16 + (lane >> 4) * 4;
        #pragma unroll
        for (int ni = 0; ni < 4; ++ni) {
            const int cg = col0 + wn * 64 + ni * 16 + (lane & 15);
            const float bv = bias[cg];
            if (EPI == 1) {
                #pragma unroll
                for (int r = 0; r < 4; ++r)
                    fo[(size_t)(rg + r) * N + cg] = acc[mi][ni][r] + bv;
            } else {
                const int region = col0 >> 10;
                if (region < 2) {
                    unsigned short* dst = region ? ko : qo;
                    // fold softmax scale (in exp2 domain) into Q at the source
                    const float sc = region ? 1.f : 0.0450744431f;  // log2(e)/32
                    const int nn = cg - (region << 10);
                    #pragma unroll
                    for (int r = 0; r < 4; ++r)
                        dst[(size_t)(rg + r) * CEMB + nn] = f2bf((acc[mi][ni][r] + bv) * sc);
                } else {
                    const int nloc = cg - 2048;
                    const int h = nloc >> 6, d = nloc & 63;
                    const int b = rg >> 11, t = rg & 2047;
                    ushort4 pk;
                    pk.x = f2bf(acc[mi][ni][0] + bv);
                    pk.y = f2bf(acc[mi][ni][1] + bv);
                    pk.z = f2bf(acc[mi][ni][2] + bv);
                    pk.w = f2bf(acc[mi][ni][3] + bv);
                    *(ushort4*)&vo[(((size_t)b * NHEAD + h) * HDIM + d) * TSEQ + t] = pk;
                }
            }
        }
    }
}

// ---------------------------------------------------------------------------
// MFMA flash attention. Swapped QK^T, dbuf K/V, unrolled x2, hoisted addrs.
// Softmax off the critical path: mrow init 0 (exact; defer-max covers growth),
// exp2 uses current mrow immediately, max/vote runs in parallel, rescale is
// applied AFTER the PV MFMA (post-tile, exact). l kept as per-lane partials,
// reduced once in the epilogue.
// Block map (R11, verified): bh=bid&31 (head->XCD), j=bid>>5,
// qt_raw=((j&7)<<2)|(j>>3), qt=reflect(qt_raw) -> per-CU qt sum == 66.
// ---------------------------------------------------------------------------
__global__ __launch_bounds__(256) void flash_mfma(
    const unsigned short* __restrict__ qb, const unsigned short* __restrict__ kb,
    const unsigned short* __restrict__ vt, unsigned short* __restrict__ ob)
{
    const int bid = blockIdx.x;
    const int bh = bid & 31;
    const int j = bid >> 5;
    const int qt_raw = ((j & 7) << 2) | (j >> 3);
    const int qt = (qt_raw & 1) ? (31 - (qt_raw >> 1)) : (qt_raw >> 1);
    const int b = bh >> 4, h = bh & 15;
    const int q0 = qt * 64;

    __shared__ __align__(16) char sK[2][8192];
    __shared__ __align__(16) char sV[2][8192];
    __shared__ __align__(16) char sP[8192];

    const int tid = threadIdx.x;
    const int lane = tid & 63;
    const int wid = tid >> 6;
    const int g = lane >> 4;
    const int lr = lane & 15;
    const int q7 = lr & 7;

    // ---- invariant staging state (per-lane) ----
    const int srow = tid >> 3;                 // 0..31 (i=0); +32 for i=1
    const int sc2 = tid & 7;
    const int sxor = (sc2 ^ (srow & 7)) << 3;  // same for row and row+32
    const int ldst = (tid & 192) << 4;         // wave-uniform LDS sub-base

    const unsigned short* kp0 = kb + (size_t)(b * TSEQ + srow) * CEMB + h * HDIM + sxor;
    const unsigned short* kp1 = kp0 + (size_t)32 * CEMB;
    const unsigned short* vp0 = vt + (((size_t)b * NHEAD + h) * HDIM + srow) * TSEQ + sxor;
    const unsigned short* vp1 = vp0 + (size_t)32 * TSEQ;

#define STAGE(BUF)                                                  \
    do {                                                            \
        g2l16(kp0, sK[BUF] + ldst);                                 \
        g2l16(kp1, sK[BUF] + 4096 + ldst);                          \
        g2l16(vp0, sV[BUF] + ldst);                                 \
        g2l16(vp1, sV[BUF] + 4096 + ldst);                          \
        kp0 += 64 * CEMB; kp1 += 64 * CEMB;                         \
        vp0 += 64; vp1 += 64;                                       \
    } while (0)

    // stage Q (into sP) + tile 0 into buf 0
    {
        const unsigned short* qp0 = qb + (size_t)(b * TSEQ + q0 + srow) * CEMB + h * HDIM + sxor;
        g2l16(qp0, sP + ldst);
        g2l16(qp0 + (size_t)32 * CEMB, sP + 4096 + ldst);
    }
    STAGE(0);
    __syncthreads();   // drain staging

    // ---- invariant LDS addresses ----
    const int rbase = (wid * 16 + lr) * 128;     // this wave's qrow stripe
    const int cA = (g ^ q7) << 4;                // ks=0 chunk byte
    const int cB = cA ^ 0x40;                    // ks=1 chunk byte (^4 on chunk)
    const char* kA0 = sK[0] + lr * 128 + cA;     // + ni*2048 immediate
    const char* kB0 = sK[0] + lr * 128 + cB;
    const char* kA1 = sK[1] + lr * 128 + cA;
    const char* kB1 = sK[1] + lr * 128 + cB;
    const char* vA0 = sV[0] + lr * 128 + cA;
    const char* vB0 = sV[0] + lr * 128 + cB;
    const char* vA1 = sV[1] + lr * 128 + cA;
    const char* vB1 = sV[1] + lr * 128 + cB;
    const char* prA = sP + rbase + cA;
    const char* prB = sP + rbase + cB;
    char* pw[4];
    #pragma unroll
    for (int ni = 0; ni < 4; ++ni)
        pw[ni] = sP + rbase + ((((2 * ni + (g >> 1))) ^ q7) << 4) + ((g & 1) << 3);

    // Q fragments (Q staged in sP with the same layout as P)
    bf16x8 qf0 = *(const bf16x8*)prA;
    bf16x8 qf1 = *(const bf16x8*)prB;
    __syncthreads();   // all waves have Q before sP becomes the P buffer

    f32x4 o[4] = {};
    float mrow = 0.f;      // exact: defer-max covers any growth; never -inf needed
    float l_lane = 0.f;    // per-lane partial (16 keys/row); reduced in epilogue
    const int qrow_g = q0 + wid * 16 + lr;

#define COMPUTE(KA, KB, VA, VB, KT)                                           \
    do {                                                                      \
        f32x4 s[4] = {};                                                      \
        __builtin_amdgcn_s_setprio(1);                                        \
        _Pragma("unroll")                                                     \
        for (int ni = 0; ni < 4; ++ni) {                                      \
            s[ni] = __builtin_amdgcn_mfma_f32_16x16x32_bf16(                  \
                *(const bf16x8*)(KA + ni * 2048), qf0, s[ni], 0, 0, 0);       \
            s[ni] = __builtin_amdgcn_mfma_f32_16x16x32_bf16(                  \
                *(const bf16x8*)(KB + ni * 2048), qf1, s[ni], 0, 0, 0);       \
        }                                                                     \
        __builtin_amdgcn_s_setprio(0);                                        \
        if ((KT) == qt) {                                                     \
            const int k0m = (KT) * 64;                                        \
            _Pragma("unroll")                                                 \
            for (int ni = 0; ni < 4; ++ni)                                    \
                _Pragma("unroll")                                             \
                for (int r = 0; r < 4; ++r)                                   \
                    if (k0m + ni * 16 + g * 4 + r > qrow_g) s[ni][r] = -INFINITY; \
        }                                                                     \
        /* guard max: tree form, runs PARALLEL to the exp2/pack path */       \
        float v01a = fmaxf(s[0][0], s[0][1]), v01b = fmaxf(s[0][2], s[0][3]); \
        float v11a = fmaxf(s[1][0], s[1][1]), v11b = fmaxf(s[1][2], s[1][3]); \
        float v21a = fmaxf(s[2][0], s[2][1]), v21b = fmaxf(s[2][2], s[2][3]); \
        float v31a = fmaxf(s[3][0], s[3][1]), v31b = fmaxf(s[3][2], s[3][3]); \
        float v = fmaxf(fmaxf(fmaxf(v01a, v01b), fmaxf(v11a, v11b)),          \
                        fmaxf(fmaxf(v21a, v21b), fmaxf(v31a, v31b)));         \
        v = fmaxf(v, __shfl_xor(v, 16));                                      \
        v = fmaxf(v, __shfl_xor(v, 32));                                      \
        /* P = exp2(S - mrow) immediately (no wait on v) */                   \
        float ps = 0.f;                                                       \
        _Pragma("unroll")                                                     \
        for (int ni = 0; ni < 4; ++ni) {                                      \
            const float p0 = exp2f(s[ni][0] - mrow);                          \
            const float p1 = exp2f(s[ni][1] - mrow);                          \
            const float p2 = exp2f(s[ni][2] - mrow);                          \
            const float p3 = exp2f(s[ni][3] - mrow);                          \
            ps += (p0 + p1) + (p2 + p3);                                      \
            uint2 w;                                                          \
            w.x = pkbf(p0, p1);                                               \
            w.y = pkbf(p2, p3);                                               \
            *(uint2*)pw[ni] = w;                                              \
        }                                                                     \
        l_lane += ps;                                                         \
        asm volatile("s_waitcnt lgkmcnt(0)" ::: "memory");                    \
        bf16x8 pf0 = *(const bf16x8*)prA;                                     \
        bf16x8 pf1 = *(const bf16x8*)prB;                                     \
        __builtin_amdgcn_s_setprio(1);                                        \
        _Pragma("unroll")                                                     \
        for (int ni = 0; ni < 4; ++ni) {                                      \
            o[ni] = __builtin_amdgcn_mfma_f32_16x16x32_bf16(                  \
                *(const bf16x8*)(VA + ni * 2048), pf0, o[ni], 0, 0, 0);       \
            o[ni] = __builtin_amdgcn_mfma_f32_16x16x32_bf16(                  \
                *(const bf16x8*)(VB + ni * 2048), pf1, o[ni], 0, 0, 0);       \
        }                                                                     \
        __builtin_amdgcn_s_setprio(0);                                        \
        /* post-tile rescale: rare; exact (this tile used old mrow throughout) */ \
        if (!__all(v <= mrow + 8.f)) {                                        \
            const float mnew = fmaxf(mrow, v);                                \
            const float sc = exp2f(mrow - mnew);                              \
            l_lane *= sc;                                                     \
            _Pragma("unroll")                                                 \
            for (int ni = 0; ni < 4; ++ni)                                    \
                _Pragma("unroll")                                             \
                for (int r = 0; r < 4; ++r)                                   \
                    o[ni][r] *= sc;                                           \
            mrow = mnew;                                                      \
        }                                                                     \
    } while (0)

    for (int kt = 0; kt <= qt; kt += 2) {
        // phase A: compute buf0 (tile kt), prefetch tile kt+1 -> buf1
        if (kt + 1 <= qt) STAGE(1);
        COMPUTE(kA0, kB0, vA0, vB0, kt);
        __syncthreads();  // drains prefetch vmcnt + LDS readers
        if (kt + 1 <= qt) {
            // phase B: compute buf1 (tile kt+1), prefetch tile kt+2 -> buf0
            if (kt + 2 <= qt) STAGE(0);
            COMPUTE(kA1, kB1, vA1, vB1, kt + 1);
            __syncthreads();
        }
    }
#undef COMPUTE
#undef STAGE

    // epilogue: reduce l across the 4 lane groups (once), normalize, write O^T
    float lsum = l_lane;
    lsum += __shfl_xor(lsum, 16);
    lsum += __shfl_xor(lsum, 32);
    const float linv = 1.f / lsum;
    #pragma unroll
    for (int ni = 0; ni < 4; ++ni) {
        uint2 w;
        w.x = pkbf(o[ni][0] * linv, o[ni][1] * linv);
        w.y = pkbf(o[ni][2] * linv, o[ni][3] * linv);
        *(uint2*)pw[ni] = w;
    }
    __syncthreads();
    #pragma unroll
    for (int i = 0; i < 2; ++i) {
        const int cid = i * 256 + tid;
        const int row = cid >> 3;      // qrow 0..63
        const int ch = cid & 7;        // d-chunk
        uint4 val = *(const uint4*)(sP + row * 128 + ((ch ^ (row & 7)) << 4));
        *(uint4*)&ob[(size_t)(b * TSEQ + q0 + row) * CEMB + h * HDIM + ch * 8] = val;
    }
}

// ---------------------------------------------------------------------------
extern "C" void kernel_launch(void* const* d_in, const int* in_sizes, int n_in,
                              void* d_out, int out_size, void* d_ws, size_t ws_size,
                              hipStream_t stream)
{
    (void)in_sizes; (void)n_in; (void)out_size; (void)ws_size;

    const float* x      = (const float*)d_in[0];
    const float* w_qkv  = (const float*)d_in[1];
    const float* b_qkv  = (const float*)d_in[2];
    const float* w_proj = (const float*)d_in[3];
    const float* b_proj = (const float*)d_in[4];
    float* out = (float*)d_out;

    const int M = BSZ * TSEQ;  // 4096
    unsigned short* xb     = (unsigned short*)d_ws;           // [4096][1024]
    unsigned short* wqkvT  = xb     + (size_t)M * CEMB;       // [3072][1024]
    unsigned short* wprojT = wqkvT  + (size_t)3 * CEMB * CEMB;// [1024][1024]
    unsigned short* qbuf   = wprojT + (size_t)CEMB * CEMB;    // [4096][1024] (pre-scaled)
    unsigned short* kbuf   = qbuf   + (size_t)M * CEMB;       // [4096][1024]
    unsigned short* vbuf   = kbuf   + (size_t)M * CEMB;       // [2][16][64][2048]
    unsigned short* attb   = vbuf   + (size_t)M * CEMB;       // [4096][1024]

    conv_f32_bf16<<<dim3((M * CEMB) / 2048), 256, 0, stream>>>(x, xb);
    conv_transpose_bf16<<<dim3(3 * CEMB / 32, CEMB / 32), 256, 0, stream>>>(
        w_qkv, wqkvT, CEMB, 3 * CEMB);
    conv_transpose_bf16<<<dim3(CEMB / 32, CEMB / 32), 256, 0, stream>>>(
        w_proj, wprojT, CEMB, CEMB);

    gemm_mfma<0><<<dim3(3 * CEMB / 128, M / 128), 256, 0, stream>>>(
        xb, wqkvT, b_qkv, qbuf, kbuf, vbuf, nullptr, M, 3 * CEMB, CEMB);

    flash_mfma<<<dim3(32 * 32), 256, 0, stream>>>(qbuf, kbuf, vbuf, attb);

    gemm_mfma<1><<<dim3(CEMB / 128, M / 128), 256, 0, stream>>>(
        attb, wprojT, b_proj, nullptr, nullptr, nullptr, out, M, CEMB, CEMB);
}